// Round 2
// baseline (168.650 us; speedup 1.0000x reference)
//
#include <hip/hip_runtime.h>
#include <stdint.h>

// VQ-VAE vector quantizer, MI355X — barrier-free MFMA main loop.
// z: (32, 256, 32, 32) fp32 ; embedding: (1024, 256) fp32
// out: [0, 8388608) quant_z (N,C,H,W) ; [8388608] vq_loss ; [8388609] commit_loss
//
//   argmin_k ||z-e_k||^2 = argmin_k ( ||e_k||^2 - 2 z.e_k )   [bf16 MFMA scores]
//   vq_loss = (sum_m (||z_m||^2 + s_min(m))) / (M*C), commit = 0.25*vq_loss
//
// Round-2 structure: 512 blocks x 256 thr, 64 z-rows/block. B fragments are read
// DIRECTLY from L2 (fragment-major Eb layout) into registers — no LDS staging of
// E, hence NO barriers and NO vmcnt(0) drains in the 16-tile main loop. LDS holds
// only the transposed z tile (32 KB) -> 2 independent blocks/CU overlap the
// prologue/epilogue barriers.

#define CDIM  256

// ws byte offsets
#define WS_EB     16777216u    // bf16[1024][256] in fragment-major layout (512 KB)
#define WS_ENORM  17301504u    // f32[1024]
#define WS_CNT    17436672u    // u32 completion counter
#define WS_LOSS   19664896u    // f32

// LDS byte offsets (dynamic shared, 47616 total -> 2 blocks/CU w/ ~190 VGPR)
#define L_ZS     0u            // bf16 [64 rows][256 c], XOR-granule swizzle (32768)
#define L_TILEF  32768u        // f32[32][66] transpose scratch (8448)
#define L_ENORM  41216u        // f32[1024]
#define L_ZNP    45312u        // f32[256]
#define L_CAND   46336u        // float2[128]
#define L_IDX    47360u        // i32[64]
#define LDS_TOTAL 47616
#define GT_STRIDE 67           // gather tile f32[128][67] aliased at 0 (34304 B)

typedef __attribute__((ext_vector_type(8))) short bf16x8;
typedef __attribute__((ext_vector_type(4))) float f32x4;

__device__ inline unsigned short f2bf(float f) {
  uint32_t u = __float_as_uint(f);
  return (unsigned short)((u + 0x7FFFu + ((u >> 16) & 1u)) >> 16);
}

__device__ inline void load16(const void* g, void* l) {
  __builtin_amdgcn_global_load_lds((const __attribute__((address_space(1))) void*)g,
                                   (__attribute__((address_space(3))) void*)l, 16, 0, 0);
}

// E -> bf16 Eb (fragment-major) + eNorm ; zero loss + counter. 256 blocks x 256 thr.
// Eb layout: frag(16B) for (code, kg) at ((T*4+s)*8+kg)*1024 + lrow*64 + lk*16
//   where T=code>>6, s=(code>>4)&3, lrow=code&15, frag covers c=kg*32+lk*8..+8.
// A wave's 64 lanes (lrow=l&15, lk=l>>4) thus read 1 KB CONTIGUOUS per (tile,s,kg).
__global__ void vq_prep_e(const float* __restrict__ E, char* __restrict__ ws) {
  const int w = threadIdx.x >> 6, l = threadIdx.x & 63;
  const int row = blockIdx.x * 4 + w;
  const float4 v = *(const float4*)(E + (size_t)row * CDIM + l * 4);
  ushort4 b;
  b.x = f2bf(v.x); b.y = f2bf(v.y); b.z = f2bf(v.z); b.w = f2bf(v.w);
  const int f = l >> 1, half = l & 1;         // c = l*4 -> frag f=c>>3, half of 16B
  const int kg = f >> 2, lk = f & 3;
  const int T = row >> 6, q = row & 63, s = q >> 4, lrow = q & 15;
  *(ushort4*)(ws + WS_EB +
              (size_t)(((T * 4 + s) * 8 + kg) * 1024 + lrow * 64 + lk * 16 + half * 8)) = b;
  float sq = v.x * v.x + v.y * v.y + v.z * v.z + v.w * v.w;
  #pragma unroll
  for (int m = 32; m >= 1; m >>= 1) sq += __shfl_xor(sq, m);
  if (l == 0) ((float*)(ws + WS_ENORM))[row] = sq;
  if (blockIdx.x == 0 && threadIdx.x == 0) {
    *((float*)(ws + WS_LOSS)) = 0.f;
    *((unsigned*)(ws + WS_CNT)) = 0u;
  }
}

// 512 blocks x 256 thr: 64 z-rows resident; 1024 codes streamed from L2 into regs.
__global__ __launch_bounds__(256, 2)
void vq_main(const float* __restrict__ z, const float* __restrict__ E,
             char* __restrict__ ws, float* __restrict__ out) {
  extern __shared__ char lds[];
  unsigned short* zs = (unsigned short*)(lds + L_ZS);
  float* tileF       = (float*)(lds + L_TILEF);
  float* eNormS      = (float*)(lds + L_ENORM);
  float* znPart      = (float*)(lds + L_ZNP);
  float2* cand       = (float2*)(lds + L_CAND);
  int* idxS          = (int*)(lds + L_IDX);
  float* gtile       = (float*)(lds);          // epilogue, aliases zs+tileF (dead)

  const int t = threadIdx.x, w = t >> 6, l = t & 63;
  const int mt = blockIdx.x;                   // 0..511
  const int n = mt >> 4, hw0 = (mt & 15) << 6;
  const char* Eb = ws + WS_EB;

  // eNorm -> LDS (wave-uniform dst + lane*16; drained by first __syncthreads)
  load16((const char*)(ws + WS_ENORM) + t * 16, (char*)eNormS + w * 1024);

  // ---- prologue: z (c-major) -> zs (row-major bf16, swizzled) + |z|^2 ----
  const float* zb0 = z + (size_t)n * (CDIM * 1024) + hw0;
  const int cA = (t >> 4) * 2, hA = (t & 15) * 4;   // loader: 2 c-rows x 4 hw
  const int r2 = t >> 2, csub = t & 3;              // packer: row r2, 8-c group
  float4 v0 = *(const float4*)(zb0 + (size_t)cA * 1024 + hA);
  float4 v1 = *(const float4*)(zb0 + (size_t)(cA + 1) * 1024 + hA);
  float znAcc = 0.f;
  for (int ci = 0; ci < 8; ++ci) {
    __syncthreads();                         // tileF free
    *(float4*)(tileF + cA * 66 + hA)       = v0;
    *(float4*)(tileF + (cA + 1) * 66 + hA) = v1;
    if (ci < 7) {
      const float* src = zb0 + (size_t)((ci + 1) * 32 + cA) * 1024 + hA;
      v0 = *(const float4*)(src);
      v1 = *(const float4*)(src + 1024);
    }
    __syncthreads();                         // tileF ready
    union { bf16x8 v; unsigned short u[8]; } pk;
    #pragma unroll
    for (int k = 0; k < 8; ++k) {
      const float sv = tileF[(csub * 8 + k) * 66 + r2];
      znAcc += sv * sv;
      pk.u[k] = f2bf(sv);
    }
    const int g  = ci * 4 + csub;            // logical granule 0..31
    const int gp = g ^ (r2 & 7);
    *(bf16x8*)((char*)zs + r2 * 512 + gp * 16) = pk.v;
  }
  znPart[t] = znAcc;
  __syncthreads();                           // zs + eNorm complete

  // ---- cache A fragments: per wave 32 rows x K=256 in registers ----
  const int lrow = l & 15, lk = l >> 4;
  const int rhalf = w & 1, s2 = w >> 1;      // rows half, code quarter
  bf16x8 af[2][8];
  #pragma unroll
  for (int rs = 0; rs < 2; ++rs) {
    const int r = rhalf * 32 + rs * 16 + lrow;
    #pragma unroll
    for (int kg = 0; kg < 8; ++kg) {
      const int gp = (kg * 4 + lk) ^ (r & 7);
      af[rs][kg] = *(const bf16x8*)((const char*)zs + r * 512 + gp * 16);
    }
  }

  // ---- main loop: 16 tiles x 64 codes, B frags from L2, NO barriers ----
  float bb[2][4]; int bidx[2][4];
  #pragma unroll
  for (int rs = 0; rs < 2; ++rs)
    #pragma unroll
    for (int i = 0; i < 4; ++i) { bb[rs][i] = 3.4e38f; bidx[rs][i] = 0; }

  const int laneB = lrow * 64 + lk * 16;
  const char* EbW = Eb + (size_t)s2 * 16384 + laneB;

  #pragma unroll 2
  for (int tile = 0; tile < 16; ++tile) {
    const char* bt = EbW + (size_t)tile * 32768;
    bf16x8 bf0[8], bf1[8];
    #pragma unroll
    for (int kg = 0; kg < 8; ++kg) bf0[kg] = *(const bf16x8*)(bt + kg * 1024);
    #pragma unroll
    for (int kg = 0; kg < 8; ++kg) bf1[kg] = *(const bf16x8*)(bt + 8192 + kg * 1024);
    f32x4 acc[2][2];
    #pragma unroll
    for (int rs = 0; rs < 2; ++rs)
      #pragma unroll
      for (int cs = 0; cs < 2; ++cs) acc[rs][cs] = (f32x4){0.f, 0.f, 0.f, 0.f};
    #pragma unroll
    for (int kg = 0; kg < 8; ++kg) {
      acc[0][0] = __builtin_amdgcn_mfma_f32_16x16x32_bf16(af[0][kg], bf0[kg], acc[0][0], 0, 0, 0);
      acc[1][0] = __builtin_amdgcn_mfma_f32_16x16x32_bf16(af[1][kg], bf0[kg], acc[1][0], 0, 0, 0);
      acc[0][1] = __builtin_amdgcn_mfma_f32_16x16x32_bf16(af[0][kg], bf1[kg], acc[0][1], 0, 0, 0);
      acc[1][1] = __builtin_amdgcn_mfma_f32_16x16x32_bf16(af[1][kg], bf1[kg], acc[1][1], 0, 0, 0);
    }
    // fold (codes ascending: cs=0 before cs=1; strict < keeps first index)
    #pragma unroll
    for (int cs = 0; cs < 2; ++cs) {
      const int code = tile * 64 + (s2 * 2 + cs) * 16 + lrow;
      const float eN = eNormS[code];
      #pragma unroll
      for (int rs = 0; rs < 2; ++rs)
        #pragma unroll
        for (int i = 0; i < 4; ++i) {
          const float sc = fmaf(-2.f, acc[rs][cs][i], eN);
          if (sc < bb[rs][i]) { bb[rs][i] = sc; bidx[rs][i] = code; }
        }
    }
  }

  // ---- reduce over 16 code-lanes, cross-wave combine, loss ----
  #pragma unroll
  for (int rs = 0; rs < 2; ++rs)
    #pragma unroll
    for (int i = 0; i < 4; ++i)
      #pragma unroll
      for (int m = 8; m >= 1; m >>= 1) {
        const float ob = __shfl_xor(bb[rs][i], m);
        const int   oi = __shfl_xor(bidx[rs][i], m);
        if (ob < bb[rs][i] || (ob == bb[rs][i] && oi < bidx[rs][i])) { bb[rs][i] = ob; bidx[rs][i] = oi; }
      }
  if (lrow == 0) {
    #pragma unroll
    for (int rs = 0; rs < 2; ++rs)
      #pragma unroll
      for (int i = 0; i < 4; ++i) {
        float2 c2; c2.x = bb[rs][i]; c2.y = __int_as_float(bidx[rs][i]);
        cand[s2 * 64 + rhalf * 32 + rs * 16 + lk * 4 + i] = c2;
      }
  }
  __syncthreads();
  if (t < 64) {
    const float2 ca = cand[t], cb = cand[64 + t];
    float best = ca.x; int bi = __float_as_int(ca.y);
    const int b2 = __float_as_int(cb.y);
    if (cb.x < best || (cb.x == best && b2 < bi)) { best = cb.x; bi = b2; }
    idxS[t] = bi;
    float d = znPart[t * 4] + znPart[t * 4 + 1] + znPart[t * 4 + 2] + znPart[t * 4 + 3] + best;
    #pragma unroll
    for (int m = 32; m >= 1; m >>= 1) d += __shfl_xor(d, m);
    if (t == 0) atomicAdd((float*)(ws + WS_LOSS), d);
  }
  __syncthreads();                           // idxS ready; zs/tileF dead

  // ---- fused gather: quant_z = E[idx] (f32 exact), 2 c-passes of 128 ----
  const int rIdx = t >> 2, qg = t & 3;
  const int gidx = idxS[rIdx];
  const float* erow = E + (size_t)gidx * CDIM;
  float* obase = out + (size_t)n * (CDIM * 1024) + hw0;
  const int ci2 = t >> 4, hwq = t & 15;
  #pragma unroll
  for (int p = 0; p < 2; ++p) {
    #pragma unroll
    for (int j = 0; j < 8; ++j) {
      const int co = (qg + j * 4) * 4;       // 0..124
      const float4 v = *(const float4*)(erow + p * 128 + co);
      gtile[(co + 0) * GT_STRIDE + rIdx] = v.x;
      gtile[(co + 1) * GT_STRIDE + rIdx] = v.y;
      gtile[(co + 2) * GT_STRIDE + rIdx] = v.z;
      gtile[(co + 3) * GT_STRIDE + rIdx] = v.w;
    }
    __syncthreads();
    #pragma unroll
    for (int j = 0; j < 8; ++j) {
      const int cl = ci2 + j * 16;
      float4 v;
      v.x = gtile[cl * GT_STRIDE + hwq * 4 + 0];
      v.y = gtile[cl * GT_STRIDE + hwq * 4 + 1];
      v.z = gtile[cl * GT_STRIDE + hwq * 4 + 2];
      v.w = gtile[cl * GT_STRIDE + hwq * 4 + 3];
      *(float4*)(obase + (size_t)(p * 128 + cl) * 1024 + hwq * 4) = v;
    }
    if (p == 0) __syncthreads();             // gtile reads done before pass-1 writes
  }

  // ---- last-block loss finalize ----
  if (t == 0) {
    __threadfence();
    const unsigned done = atomicAdd((unsigned*)(ws + WS_CNT), 1u);
    if (done == 511u) {
      const float L = atomicAdd((float*)(ws + WS_LOSS), 0.0f) * (1.0f / 8388608.0f);
      out[8388608] = L;
      out[8388609] = 0.25f * L;
    }
  }
}

extern "C" void kernel_launch(void* const* d_in, const int* in_sizes, int n_in,
                              void* d_out, int out_size, void* d_ws, size_t ws_size,
                              hipStream_t stream) {
  const float* z = (const float*)d_in[0];
  const float* E = (const float*)d_in[1];
  float* out = (float*)d_out;
  char*  ws  = (char*)d_ws;

  static const int kLds = LDS_TOTAL;
  (void)hipFuncSetAttribute((const void*)vq_main,
                            hipFuncAttributeMaxDynamicSharedMemorySize, kLds);

  vq_prep_e <<<256, 256, 0, stream>>>(E, ws);
  vq_main   <<<512, 256, kLds, stream>>>(z, E, ws, out);
}

// Round 3
// 124.470 us; speedup vs baseline: 1.3549x; 1.3549x over previous
//
#include <hip/hip_runtime.h>
#include <stdint.h>

// VQ-VAE vector quantizer, MI355X — counted-vmcnt pipelined MFMA main loop.
// z: (32, 256, 32, 32) fp32 ; embedding: (1024, 256) fp32
// out: [0, 8388608) quant_z (N,C,H,W) ; [8388608] vq_loss ; [8388609] commit_loss
//
//   argmin_k ||z-e_k||^2 = argmin_k ( ||e_k||^2 - 2 z.e_k )   [bf16 MFMA scores]
//   vq_loss = (sum_m (||z_m||^2 + s_min(m))) / (M*C), commit = 0.25*vq_loss
//
// Round-3: round-1 structure (256 blocks x 512 thr, 128 rows/block, LDS-staged E)
// but the main loop is a depth-2 software pipeline: 32 tiles x 32 codes, TRIPLE-
// buffered es, per-tile fence = sched_barrier + s_waitcnt vmcnt(2) + raw s_barrier.
// Staged loads for tile t+2 stay in flight ACROSS the barrier (T3+T4 template);
// no vmcnt(0) drain until the epilogue fence (t=30).

#define CDIM  256

// ws byte offsets
#define WS_EB     16777216u    // bf16[1024][256] row-major (512 KB)
#define WS_ENORM  17301504u    // f32[1024]
#define WS_CNT    17436672u    // u32 completion counter
#define WS_LOSS   19664896u    // f32

// LDS byte offsets (dynamic shared, 123392 total)
#define L_ZS     0u            // bf16 [128 rows][256 c], XOR-granule swizzle (65536)
#define L_ES     65536u        // bf16 [3][32 codes][256 c], swizzled, triple buffer
#define L_TILEF  81920u        // f32[32][132] transpose scratch (aliases es buf1+2;
                               //   tile1 staged into buf1 only AFTER transpose)
#define L_ENORM  114688u       // f32[1024]
#define L_ZNP    118784u       // f32[128][4]
#define L_CAND   120832u       // float2[256]
#define L_IDX    122880u       // i32[128]
#define LDS_TOTAL 123392
#define GT_STRIDE 132          // gather tile f32[128 c][132] aliased at 0 (67584 B)

typedef __attribute__((ext_vector_type(8))) short bf16x8;
typedef __attribute__((ext_vector_type(4))) float f32x4;

__device__ inline unsigned short f2bf(float f) {
  uint32_t u = __float_as_uint(f);
  return (unsigned short)((u + 0x7FFFu + ((u >> 16) & 1u)) >> 16);
}

__device__ inline void load16(const void* g, void* l) {
  __builtin_amdgcn_global_load_lds((const __attribute__((address_space(1))) void*)g,
                                   (__attribute__((address_space(3))) void*)l, 16, 0, 0);
}

// E -> bf16 Eb (row-major) + eNorm ; zero loss + counter. 256 blocks x 256 thr.
__global__ void vq_prep_e(const float* __restrict__ E, char* __restrict__ ws) {
  const int w = threadIdx.x >> 6, l = threadIdx.x & 63;
  const int row = blockIdx.x * 4 + w;
  const float4 v = *(const float4*)(E + (size_t)row * CDIM + l * 4);
  ushort4 b;
  b.x = f2bf(v.x); b.y = f2bf(v.y); b.z = f2bf(v.z); b.w = f2bf(v.w);
  *(ushort4*)(ws + WS_EB + (size_t)row * 512 + l * 8) = b;
  float s = v.x * v.x + v.y * v.y + v.z * v.z + v.w * v.w;
  #pragma unroll
  for (int m = 32; m >= 1; m >>= 1) s += __shfl_xor(s, m);
  if (l == 0) ((float*)(ws + WS_ENORM))[row] = s;
  if (blockIdx.x == 0 && threadIdx.x == 0) {
    *((float*)(ws + WS_LOSS)) = 0.f;
    *((unsigned*)(ws + WS_CNT)) = 0u;
  }
}

// One block per CU, 8 waves: 128 z-rows resident; 1024 codes streamed; argmin +
// loss + fused quant_z gather + last-block loss finalize.
__global__ __launch_bounds__(512, 2)
void vq_main(const float* __restrict__ z, const float* __restrict__ E,
             char* __restrict__ ws, float* __restrict__ out) {
  extern __shared__ char lds[];
  unsigned short* zs = (unsigned short*)(lds + L_ZS);
  char* esb          = lds + L_ES;
  float* tileF       = (float*)(lds + L_TILEF);
  float* eNormS      = (float*)(lds + L_ENORM);
  float* znPart      = (float*)(lds + L_ZNP);
  float2* cand       = (float2*)(lds + L_CAND);
  int* idxS          = (int*)(lds + L_IDX);
  float* gtile       = (float*)(lds);          // epilogue, aliases zs+es (dead)

  const int t = threadIdx.x, w = t >> 6, l = t & 63;
  const int mt = blockIdx.x;                 // 0..255
  const int n = mt >> 3, hw0 = (mt & 7) << 7;
  const char* Eb = ws + WS_EB;

  // per-thread staging source offsets for one 32-code es tile (swizzle baked in)
  int srcOff[2];
  #pragma unroll
  for (int i = 0; i < 2; ++i) {
    const int j = (i * 8 + w) * 64 + l;      // LDS granule 0..1023
    const int q = j >> 5;                    // code-in-tile 0..31
    const int g = (j & 31) ^ (q & 7);        // source granule (un-swizzle)
    srcOff[i] = q * 512 + g * 16;
  }
  // stage es tile 0 into buf 0 (buf1/buf2 alias tileF: staged later) + eNorm
  #pragma unroll
  for (int i = 0; i < 2; ++i)
    load16(Eb + srcOff[i], esb + (i * 8 + w) * 1024);
  if (w < 4)
    load16((const char*)(ws + WS_ENORM) + (w * 64 + l) * 16, (char*)eNormS + w * 1024);

  // ---- prologue: z (c-major) -> zs (row-major bf16, swizzled) + |z|^2 ----
  const float* zb0 = z + (size_t)n * (CDIM * 1024) + hw0;
  const int cA = t >> 4;                     // c within 32-chunk (0..31)
  const int hA = (t & 15) * 8;               // hw offset (2 float4)
  const int r2 = (t >> 1) & 127, gsub = t & 1, ksel = t >> 8;
  const int cbase = gsub * 16 + ksel * 8;    // 8 consecutive c per thread
  float4 v0 = *(const float4*)(zb0 + (size_t)cA * 1024 + hA);
  float4 v1 = *(const float4*)(zb0 + (size_t)cA * 1024 + hA + 4);
  float znAcc = 0.f;
  for (int ci = 0; ci < 8; ++ci) {
    __syncthreads();                         // tileF free
    *(float4*)(tileF + cA * 132 + hA)     = v0;
    *(float4*)(tileF + cA * 132 + hA + 4) = v1;
    if (ci < 7) {
      const float* src = zb0 + (size_t)((ci + 1) * 32 + cA) * 1024 + hA;
      v0 = *(const float4*)(src);
      v1 = *(const float4*)(src + 4);
    }
    __syncthreads();                         // tileF ready
    union { bf16x8 v; unsigned short u[8]; } pk;
    #pragma unroll
    for (int k = 0; k < 8; ++k) {
      const float sv = tileF[(cbase + k) * 132 + r2];
      znAcc += sv * sv;
      pk.u[k] = f2bf(sv);
    }
    const int g  = ci * 4 + gsub * 2 + ksel; // logical granule 0..31
    const int gp = g ^ (r2 & 7);
    *(bf16x8*)((char*)zs + r2 * 512 + gp * 16) = pk.v;
  }
  znPart[r2 * 4 + gsub * 2 + ksel] = znAcc;
  // stage es tile 1 into buf 1 (tileF now dead)
  #pragma unroll
  for (int i = 0; i < 2; ++i)
    load16(Eb + 16384 + srcOff[i], esb + 16384 + (i * 8 + w) * 1024);
  __syncthreads();                           // full drain: zs, eNorm, tiles 0+1 ready

  // ---- cache A fragments: per wave 32 rows x K=256 in registers ----
  const int rquad = w & 3, chalf = w >> 2;   // rows quarter, code half
  const int lrow = l & 15, lk = l >> 4;
  bf16x8 af[2][8];
  #pragma unroll
  for (int rs = 0; rs < 2; ++rs) {
    const int r = rquad * 32 + rs * 16 + lrow;
    #pragma unroll
    for (int kg = 0; kg < 8; ++kg) {
      const int gp = (kg * 4 + lk) ^ (r & 7);
      af[rs][kg] = *(const bf16x8*)((const char*)zs + r * 512 + gp * 16);
    }
  }

  // ---- main loop: 32 tiles x 32 codes, depth-2 pipeline, triple buffer ----
  float bb[2][4]; int bidx[2][4];
  #pragma unroll
  for (int rs = 0; rs < 2; ++rs)
    #pragma unroll
    for (int i = 0; i < 4; ++i) { bb[rs][i] = 3.4e38f; bidx[rs][i] = 0; }

  const int q = chalf * 16 + lrow;           // code-in-tile for this lane
  int bR = 0, bW = 2;                        // read buf = tile%3, write buf = (tile+2)%3
  for (int tile = 0; tile < 32; ++tile) {
    if (tile < 30) {                         // issue stage of tile+2 (rides across fences)
      const char* src = Eb + (size_t)(tile + 2) * 16384;
      char* dst = esb + bW * 16384;
      load16(src + srcOff[0], dst + w * 1024);
      load16(src + srcOff[1], dst + (8 + w) * 1024);
    }
    f32x4 acc[2];
    acc[0] = (f32x4){0.f, 0.f, 0.f, 0.f};
    acc[1] = (f32x4){0.f, 0.f, 0.f, 0.f};
    const char* ebase = (const char*)esb + bR * 16384 + q * 512;
    #pragma unroll
    for (int kg = 0; kg < 8; ++kg) {
      const int gp = (kg * 4 + lk) ^ (q & 7);
      const bf16x8 bf = *(const bf16x8*)(ebase + gp * 16);
      acc[0] = __builtin_amdgcn_mfma_f32_16x16x32_bf16(af[0][kg], bf, acc[0], 0, 0, 0);
      acc[1] = __builtin_amdgcn_mfma_f32_16x16x32_bf16(af[1][kg], bf, acc[1], 0, 0, 0);
    }
    // fold scores (codes ascending over tiles; strict < keeps first index)
    const int code = tile * 32 + q;
    const float eN = eNormS[code];
    #pragma unroll
    for (int rs = 0; rs < 2; ++rs)
      #pragma unroll
      for (int i = 0; i < 4; ++i) {
        const float sc = fmaf(-2.f, acc[rs][i], eN);
        if (sc < bb[rs][i]) { bb[rs][i] = sc; bidx[rs][i] = code; }
      }
    // fence: retire tile t+1's loads (2 oldest); keep tile t+2's in flight
    if (tile < 31) {
      __builtin_amdgcn_sched_barrier(0);
      if (tile < 30) asm volatile("s_waitcnt vmcnt(2)" ::: "memory");
      else           asm volatile("s_waitcnt vmcnt(0)" ::: "memory");
      __builtin_amdgcn_s_barrier();
      __builtin_amdgcn_sched_barrier(0);
    }
    bR = (bR == 2) ? 0 : bR + 1;
    bW = (bW == 2) ? 0 : bW + 1;
  }

  // ---- reduce over 16 code-lanes, cross-wave combine, loss ----
  #pragma unroll
  for (int rs = 0; rs < 2; ++rs)
    #pragma unroll
    for (int i = 0; i < 4; ++i)
      #pragma unroll
      for (int m = 8; m >= 1; m >>= 1) {
        const float ob = __shfl_xor(bb[rs][i], m);
        const int   oi = __shfl_xor(bidx[rs][i], m);
        if (ob < bb[rs][i] || (ob == bb[rs][i] && oi < bidx[rs][i])) { bb[rs][i] = ob; bidx[rs][i] = oi; }
      }
  if (lrow == 0) {
    #pragma unroll
    for (int rs = 0; rs < 2; ++rs)
      #pragma unroll
      for (int i = 0; i < 4; ++i) {
        float2 c2; c2.x = bb[rs][i]; c2.y = __int_as_float(bidx[rs][i]);
        cand[chalf * 128 + rquad * 32 + rs * 16 + lk * 4 + i] = c2;
      }
  }
  __syncthreads();
  if (t < 128) {
    const float2 ca = cand[t], cb = cand[128 + t];
    float best = ca.x; int bi = __float_as_int(ca.y);
    const int b2 = __float_as_int(cb.y);
    if (cb.x < best || (cb.x == best && b2 < bi)) { best = cb.x; bi = b2; }
    idxS[t] = bi;
    float d = znPart[t * 4] + znPart[t * 4 + 1] + znPart[t * 4 + 2] + znPart[t * 4 + 3] + best;
    #pragma unroll
    for (int m = 32; m >= 1; m >>= 1) d += __shfl_xor(d, m);
    if ((t & 63) == 0) atomicAdd((float*)(ws + WS_LOSS), d);
  }
  __syncthreads();                           // idxS ready; zs/es dead

  // ---- fused gather: quant_z = E[idx] (f32 exact), 2 c-passes of 128 ----
  const int rIdx = t >> 2, qg = t & 3;
  const int gidx = idxS[rIdx];
  const float* erow = E + (size_t)gidx * CDIM;
  float* obase = out + (size_t)n * (CDIM * 1024) + hw0;
  #pragma unroll
  for (int p = 0; p < 2; ++p) {
    #pragma unroll
    for (int j = 0; j < 8; ++j) {
      const int cc = qg + j * 4;             // 0..31
      const float4 v = *(const float4*)(erow + p * 128 + cc * 4);
      gtile[(cc * 4 + 0) * GT_STRIDE + rIdx] = v.x;
      gtile[(cc * 4 + 1) * GT_STRIDE + rIdx] = v.y;
      gtile[(cc * 4 + 2) * GT_STRIDE + rIdx] = v.z;
      gtile[(cc * 4 + 3) * GT_STRIDE + rIdx] = v.w;
    }
    __syncthreads();
    #pragma unroll
    for (int j = 0; j < 8; ++j) {
      const int c = (t >> 5) + j * 16;       // 0..127
      const int hw = (t & 31) * 4;           // 0..124
      float4 v;
      v.x = gtile[c * GT_STRIDE + hw + 0];
      v.y = gtile[c * GT_STRIDE + hw + 1];
      v.z = gtile[c * GT_STRIDE + hw + 2];
      v.w = gtile[c * GT_STRIDE + hw + 3];
      *(float4*)(obase + (size_t)(p * 128 + c) * 1024 + hw) = v;
    }
    if (p == 0) __syncthreads();             // gtile reads done before pass-1 writes
  }

  // ---- last-block loss finalize ----
  if (t == 0) {
    __threadfence();
    const unsigned done = atomicAdd((unsigned*)(ws + WS_CNT), 1u);
    if (done == 255u) {
      const float L = atomicAdd((float*)(ws + WS_LOSS), 0.0f) * (1.0f / 8388608.0f);
      out[8388608] = L;
      out[8388609] = 0.25f * L;
    }
  }
}

extern "C" void kernel_launch(void* const* d_in, const int* in_sizes, int n_in,
                              void* d_out, int out_size, void* d_ws, size_t ws_size,
                              hipStream_t stream) {
  const float* z = (const float*)d_in[0];
  const float* E = (const float*)d_in[1];
  float* out = (float*)d_out;
  char*  ws  = (char*)d_ws;

  static const int kLds = LDS_TOTAL;
  (void)hipFuncSetAttribute((const void*)vq_main,
                            hipFuncAttributeMaxDynamicSharedMemorySize, kLds);

  vq_prep_e <<<256, 256, 0, stream>>>(E, ws);
  vq_main   <<<256, 512, kLds, stream>>>(z, E, ws, out);
}